// Round 6
// baseline (303.801 us; speedup 1.0000x reference)
//
#include <hip/hip_runtime.h>
#include <hip/hip_bf16.h>

constexpr int TTOK  = 16384;   // B*S = 8*2048
constexpr int DDIM  = 512;
constexpr int FFDIM = 2048;
constexpr int NEXP  = 8;
constexpr int GB_TOK = 16;             // tokens per gate/scatter block
constexpr int NGB    = TTOK / GB_TOK;  // 1024
constexpr int MAXTILES = TTOK / 128 + NEXP;  // 136: worst-case M-tiles over all experts
constexpr int TRW1_BLOCKS = 4096;      // 512 tiles/expert * 8 (64x32 tiles)
constexpr int TRW2_XBLK   = 256;       // x-extent of W2-transpose range in gemm1 grid (x16 y = 4096)

typedef __attribute__((ext_vector_type(8))) short short8_t;
typedef __attribute__((ext_vector_type(4))) float f32x4_t;

__device__ __forceinline__ unsigned short f2bf(float f) {
    union { float f; unsigned u; } v; v.f = f;
    return (unsigned short)((v.u + 0x7fffu + ((v.u >> 16) & 1u)) >> 16);  // RNE
}

__device__ __forceinline__ void gl_lds16(const void* g, void* l) {
    __builtin_amdgcn_global_load_lds(
        (const __attribute__((address_space(1))) void*)g,
        (__attribute__((address_space(3))) void*)l,
        16, 0, 0);
}

// ---------------- fast 64(r)x32(c) transpose+cast tile (proven R4)
__device__ __forceinline__ void tr_tile(const float* __restrict__ src,
                                        unsigned short* __restrict__ dst,
                                        int R, int C, int tileId, float* lds) {
    int tilesC = C / 32;
    int c0 = (tileId % tilesC) * 32;
    int r0 = (tileId / tilesC) * 64;
    int t = threadIdx.x;
    int lr = t >> 3;            // 0..31
    int ls = t & 7;             // float4 slot
    #pragma unroll
    for (int rb = 0; rb < 2; rb++) {
        int row = rb * 32 + lr;
        float4 v = *(const float4*)(src + (size_t)(r0 + row) * C + c0 + 4 * ls);
        int p4 = (4 * ls) ^ (8 * ((row >> 3) & 3));
        *(float4*)(lds + row * 36 + p4) = v;
    }
    __syncthreads();
    int c = t >> 3;             // dst row (= src col) 0..31
    int b = t & 7;              // r-block
    union { short8_t v; unsigned short s[8]; } o;
    #pragma unroll
    for (int j = 0; j < 8; j++) {
        int r = 8 * b + j;
        int p = c ^ (8 * ((r >> 3) & 3));
        o.s[j] = f2bf(lds[r * 36 + p]);
    }
    *(short8_t*)(dst + (size_t)(c0 + c) * R + r0 + 8 * b) = o.v;
}

// ---------------- fused prep: gate (blocks [0,1024)) + W1 transpose/cast (rest)
__global__ __launch_bounds__(256) void prep_kernel(const float* __restrict__ x,
                                                   const float* __restrict__ Wg,
                                                   const float* __restrict__ bg,
                                                   int* __restrict__ route,
                                                   float* __restrict__ pmax,
                                                   int* __restrict__ blockCounts,
                                                   const float* __restrict__ W1,
                                                   unsigned short* __restrict__ W1T) {
    int tid = threadIdx.x;
    if (blockIdx.x >= NGB) {
        __shared__ __align__(16) float tlds[64 * 36];
        int id = blockIdx.x - NGB;             // 0..4095
        int e = id >> 9;                       // 512 tiles per expert
        int tile = id & 511;
        tr_tile(W1 + (size_t)e * DDIM * FFDIM, W1T + (size_t)e * DDIM * FFDIM,
                DDIM, FFDIM, tile, tlds);
        return;
    }
    // ---- gating: Wg in registers, f64 logit accum (routing-stable), f32 softmax tail
    __shared__ int cnt[NEXP];
    __shared__ float bgs[NEXP];
    int gb = blockIdx.x;
    if (tid < NEXP) { cnt[tid] = 0; bgs[tid] = bg[tid]; }
    __syncthreads();
    int wave = tid >> 6, lane = tid & 63;
    float w[8][8];
    #pragma unroll
    for (int jj = 0; jj < 8; jj++) {
        float4 a = *(const float4*)(Wg + (size_t)(lane * 8 + jj) * NEXP);
        float4 b = *(const float4*)(Wg + (size_t)(lane * 8 + jj) * NEXP + 4);
        w[jj][0] = a.x; w[jj][1] = a.y; w[jj][2] = a.z; w[jj][3] = a.w;
        w[jj][4] = b.x; w[jj][5] = b.y; w[jj][6] = b.z; w[jj][7] = b.w;
    }
    int tbase = gb * GB_TOK + wave * 4;
    for (int it = 0; it < 4; it++) {
        int t = tbase + it;
        float4 xa = *(const float4*)(x + (size_t)t * DDIM + lane * 8);
        float4 xb = *(const float4*)(x + (size_t)t * DDIM + lane * 8 + 4);
        float xs[8] = {xa.x, xa.y, xa.z, xa.w, xb.x, xb.y, xb.z, xb.w};
        double acc[NEXP];
        #pragma unroll
        for (int e = 0; e < NEXP; e++) acc[e] = 0.0;
        #pragma unroll
        for (int jj = 0; jj < 8; jj++) {
            double xv = (double)xs[jj];
            #pragma unroll
            for (int e = 0; e < NEXP; e++) acc[e] += xv * (double)w[jj][e];
        }
        #pragma unroll
        for (int off = 32; off > 0; off >>= 1) {
            #pragma unroll
            for (int e = 0; e < NEXP; e++) acc[e] += __shfl_down(acc[e], off);
        }
        if (lane == 0) {
            double l[NEXP];
            #pragma unroll
            for (int e = 0; e < NEXP; e++) l[e] = acc[e] + (double)bgs[e];
            int r = 0; double lm = l[0];
            #pragma unroll
            for (int e = 1; e < NEXP; e++) if (l[e] > lm) { lm = l[e]; r = e; }
            float s = 0.0f;                          // f32 softmax (matches f32 reference)
            #pragma unroll
            for (int e = 0; e < NEXP; e++) s += __expf((float)(l[e] - lm));
            route[t] = r;
            pmax[t] = 1.0f / s;
            atomicAdd(&cnt[r], 1);
        }
    }
    __syncthreads();
    if (tid < NEXP) blockCounts[gb * NEXP + tid] = cnt[tid];
}

// ---------------- scatter v2: inlines the offset computation (no separate scan kernel).
// Each block reduces blockCounts (L2-resident 32 KB) into {total[e], prefix-below-bb[e]};
// block 0 also publishes segPrefix/tilePrefix for the GEMMs.
__global__ __launch_bounds__(256) void scatter_kernel(const float* __restrict__ x,
                                                      const int* __restrict__ route,
                                                      const float* __restrict__ pmax,
                                                      const int* __restrict__ blockCounts,
                                                      unsigned short* __restrict__ Xs,
                                                      int* __restrict__ segPrefix,
                                                      int* __restrict__ tilePrefix) {
    int tid = threadIdx.x;
    int bb = blockIdx.x;
    int wave = tid >> 6, lane = tid & 63;

    int tot[NEXP], pre[NEXP];
    #pragma unroll
    for (int e = 0; e < NEXP; e++) { tot[e] = 0; pre[e] = 0; }
    for (int b = tid; b < NGB; b += 256) {
        #pragma unroll
        for (int e = 0; e < NEXP; e++) {
            int c = blockCounts[b * NEXP + e];
            tot[e] += c;
            if (b < bb) pre[e] += c;
        }
    }
    #pragma unroll
    for (int off = 32; off > 0; off >>= 1) {
        #pragma unroll
        for (int e = 0; e < NEXP; e++) {
            tot[e] += __shfl_down(tot[e], off);
            pre[e] += __shfl_down(pre[e], off);
        }
    }
    __shared__ int stot[4][NEXP], spre[4][NEXP];
    __shared__ int boff[NEXP];
    if (lane == 0) {
        #pragma unroll
        for (int e = 0; e < NEXP; e++) { stot[wave][e] = tot[e]; spre[wave][e] = pre[e]; }
    }
    __syncthreads();
    if (tid == 0) {
        int T[NEXP], P[NEXP];
        #pragma unroll
        for (int e = 0; e < NEXP; e++) {
            T[e] = stot[0][e] + stot[1][e] + stot[2][e] + stot[3][e];
            P[e] = spre[0][e] + spre[1][e] + spre[2][e] + spre[3][e];
        }
        int s = 0;
        #pragma unroll
        for (int e = 0; e < NEXP; e++) { boff[e] = s + P[e]; s += T[e]; }
        if (bb == 0) {
            int ss = 0, tp = 0;
            segPrefix[0] = 0; tilePrefix[0] = 0;
            #pragma unroll
            for (int e = 0; e < NEXP; e++) {
                ss += T[e]; tp += (T[e] + 127) >> 7;
                segPrefix[e + 1] = ss; tilePrefix[e + 1] = tp;
            }
        }
    }
    __syncthreads();

    __shared__ int dstL[GB_TOK];
    __shared__ float pmL[GB_TOK];
    if (tid < GB_TOK) {
        int t = bb * GB_TOK + tid;
        int r = route[t];
        unsigned long long ltmask = (tid == 0) ? 0ull : ((~0ull) >> (64 - tid));
        int rank = 0;
        #pragma unroll
        for (int e = 0; e < NEXP; e++) {
            unsigned long long m = __ballot(r == e);
            if (r == e) rank = __popcll(m & ltmask);
        }
        dstL[tid] = boff[r] + rank;
        pmL[tid] = pmax[t];
    }
    __syncthreads();
    for (int rr = 0; rr < 4; rr++) {
        int rowl = wave * 4 + rr;
        int t = bb * GB_TOK + rowl;
        float pm = pmL[rowl];
        const float4* xr = (const float4*)(x + (size_t)t * DDIM) + lane * 2;
        float4 a = xr[0], b = xr[1];
        union { short8_t v; unsigned short s[8]; } o;
        o.s[0] = f2bf(a.x * pm); o.s[1] = f2bf(a.y * pm);
        o.s[2] = f2bf(a.z * pm); o.s[3] = f2bf(a.w * pm);
        o.s[4] = f2bf(b.x * pm); o.s[5] = f2bf(b.y * pm);
        o.s[6] = f2bf(b.z * pm); o.s[7] = f2bf(b.w * pm);
        *(short8_t*)(Xs + (size_t)dstL[rowl] * DDIM + lane * 8) = o.v;
    }
}

// ============================================================================
// GEMM1 fused (proven R4): 128x128/BK=64 2-barrier structure + W2-transpose
// piggyback blocks sharing one 32 KB SMEM region. bf16 out + ReLU + bias.
// ============================================================================
__global__ __launch_bounds__(256) void gemm1_fused(const unsigned short* __restrict__ A,
                                                   const unsigned short* __restrict__ Bt,
                                                   const float* __restrict__ bias,
                                                   unsigned short* __restrict__ C,
                                                   const int* __restrict__ segPrefix,
                                                   const int* __restrict__ tilePrefix,
                                                   const float* __restrict__ W2,
                                                   unsigned short* __restrict__ W2T) {
    constexpr int K = DDIM, N = FFDIM;
    __shared__ __align__(16) unsigned short SMEM[16384];   // 32 KB shared by both roles

    if (blockIdx.x >= MAXTILES) {
        int id = (blockIdx.x - MAXTILES) * 16 + blockIdx.y;  // 0..4095
        int e = id >> 9;
        int tile = id & 511;
        tr_tile(W2 + (size_t)e * DDIM * FFDIM, W2T + (size_t)e * DDIM * FFDIM,
                FFDIM, DDIM, tile, (float*)SMEM);
        return;
    }

    int bx = blockIdx.x;
    bx = (bx & 7) * (MAXTILES / 8) + (bx >> 3);   // bijective XCD chunking (136 % 8 == 0)
    int t = bx;
    if (t >= tilePrefix[NEXP]) return;
    int e = 0;
    #pragma unroll
    for (int i = 1; i <= NEXP; i++) e += (t >= tilePrefix[i]) ? 1 : 0;
    int seg1 = segPrefix[e + 1];
    int m0 = segPrefix[e] + (t - tilePrefix[e]) * 128;
    int n0 = blockIdx.y * 128;

    unsigned short* As = SMEM;
    unsigned short* Bs = SMEM + 8192;

    int tid = threadIdx.x, wave = tid >> 6, lane = tid & 63;
    const unsigned short* Bte = Bt + (size_t)e * N * K;

    int srow = lane >> 2;
    int sg   = (lane & 3) ^ ((lane >> 2) & 3) ^ ((lane >> 4) & 3);
    int scol = sg * 8;

    f32x4_t acc[4][4];
    #pragma unroll
    for (int i = 0; i < 4; i++)
        #pragma unroll
        for (int j = 0; j < 4; j++) acc[i][j] = (f32x4_t){0.f, 0.f, 0.f, 0.f};

    int wm = (wave & 1) * 64;
    int wn = (wave >> 1) * 64;
    int frow = lane & 15;
    int gr = lane >> 4;
    int fswz = (gr ^ (frow & 3) ^ ((frow >> 2) & 3)) * 8;

    int reg0 = wave * 2;
    int arow0 = m0 + reg0 * 16 + srow;
    arow0 = arow0 < TTOK ? arow0 : TTOK - 1;
    int arow1 = m0 + (reg0 + 1) * 16 + srow;
    arow1 = arow1 < TTOK ? arow1 : TTOK - 1;
    const unsigned short* aptr0 = A + (size_t)arow0 * K + scol;
    const unsigned short* aptr1 = A + (size_t)arow1 * K + scol;
    const unsigned short* bptr0 = Bte + (size_t)(n0 + reg0 * 16 + srow) * K + scol;
    const unsigned short* bptr1 = Bte + (size_t)(n0 + (reg0 + 1) * 16 + srow) * K + scol;

    #pragma unroll
    for (int kc = 0; kc < K; kc += 64) {
        #pragma unroll
        for (int p = 0; p < 2; p++) {
            gl_lds16(aptr0 + kc + p * 32, &As[p * 4096 + reg0 * 512]);
            gl_lds16(aptr1 + kc + p * 32, &As[p * 4096 + (reg0 + 1) * 512]);
            gl_lds16(bptr0 + kc + p * 32, &Bs[p * 4096 + reg0 * 512]);
            gl_lds16(bptr1 + kc + p * 32, &Bs[p * 4096 + (reg0 + 1) * 512]);
        }
        __syncthreads();
        #pragma unroll
        for (int p = 0; p < 2; p++) {
            short8_t af[4], bfr[4];
            #pragma unroll
            for (int i = 0; i < 4; i++)
                af[i] = *(const short8_t*)&As[p * 4096 + (wm + i * 16 + frow) * 32 + fswz];
            #pragma unroll
            for (int j = 0; j < 4; j++)
                bfr[j] = *(const short8_t*)&Bs[p * 4096 + (wn + j * 16 + frow) * 32 + fswz];
            #pragma unroll
            for (int i = 0; i < 4; i++)
                #pragma unroll
                for (int j = 0; j < 4; j++)
                    acc[i][j] = __builtin_amdgcn_mfma_f32_16x16x32_bf16(af[i], bfr[j], acc[i][j], 0, 0, 0);
        }
        __syncthreads();
    }

    int quad = lane >> 4;
    int colb = lane & 15;
    float bv[4];
    #pragma unroll
    for (int j = 0; j < 4; j++) bv[j] = bias[(size_t)e * N + n0 + wn + j * 16 + colb];

    unsigned short* cbuf = As;
    #pragma unroll
    for (int p = 0; p < 2; p++) {
        __syncthreads();
        if ((wave >> 1) == p) {
            #pragma unroll
            for (int i = 0; i < 4; i++)
                #pragma unroll
                for (int j = 0; j < 4; j++)
                    #pragma unroll
                    for (int r = 0; r < 4; r++) {
                        float v = acc[i][j][r] + bv[j];
                        v = fmaxf(v, 0.0f);
                        int wrow = wm + i * 16 + quad * 4 + r;
                        int cc = (j * 16 + colb) ^ (((wrow >> 3) & 1) * 16);
                        cbuf[wrow * 72 + cc] = f2bf(v);
                    }
        }
        __syncthreads();
        int row = tid >> 1, ch = (tid & 1) * 32;
        int grow = m0 + row;
        if (grow < seg1) {
            #pragma unroll
            for (int k = 0; k < 4; k++) {
                int vv = (ch + k * 8) ^ (((row >> 3) & 1) * 16);
                short8_t v = *(const short8_t*)&cbuf[row * 72 + vv];
                *(short8_t*)&C[(size_t)grow * N + n0 + p * 64 + ch + k * 8] = v;
            }
        }
    }
}

// ============================================================================
// GEMM2 v2: 128M x 64N tiles, BK=64, K=2048, fp32 out. Same proven 2-barrier
// loop, but 2x grid width (136 x 8 = 1088 blocks) and 24 KB LDS -> 6 blocks/CU:
// attacks GEMM2's TLP starvation (was 544 blocks = 2.1/CU = 8.5 waves/CU).
// Wave grid 2Mx2N: each wave 64x32 output, acc[4][2].
// ============================================================================
__global__ __launch_bounds__(256) void gemm2_seg(const unsigned short* __restrict__ A,
                                                 const unsigned short* __restrict__ Bt,
                                                 const float* __restrict__ bias,
                                                 float* __restrict__ C,
                                                 const int* __restrict__ segPrefix,
                                                 const int* __restrict__ tilePrefix) {
    constexpr int K = FFDIM, N = DDIM;
    int bx = blockIdx.x;
    bx = (bx & 7) * (MAXTILES / 8) + (bx >> 3);   // bijective XCD chunking
    int t = bx;
    if (t >= tilePrefix[NEXP]) return;
    int e = 0;
    #pragma unroll
    for (int i = 1; i <= NEXP; i++) e += (t >= tilePrefix[i]) ? 1 : 0;
    int seg1 = segPrefix[e + 1];
    int m0 = segPrefix[e] + (t - tilePrefix[e]) * 128;
    int n0 = blockIdx.y * 64;

    __shared__ unsigned short As[2 * 4096];   // 2 halves x 128 rows x 32 shorts
    __shared__ unsigned short Bs[2 * 2048];   // 2 halves x  64 rows x 32 shorts

    int tid = threadIdx.x, wave = tid >> 6, lane = tid & 63;
    const unsigned short* Bte = Bt + (size_t)e * N * K;

    int srow = lane >> 2;
    int sg   = (lane & 3) ^ ((lane >> 2) & 3) ^ ((lane >> 4) & 3);
    int scol = sg * 8;

    f32x4_t acc[4][2];
    #pragma unroll
    for (int i = 0; i < 4; i++)
        #pragma unroll
        for (int j = 0; j < 2; j++) acc[i][j] = (f32x4_t){0.f, 0.f, 0.f, 0.f};

    int wm = (wave & 1) * 64;      // M offset: waves {0,2} rows 0-63, {1,3} rows 64-127
    int wn = (wave >> 1) * 32;     // N offset: waves {0,1} cols 0-31, {2,3} cols 32-63
    int frow = lane & 15;
    int gr = lane >> 4;
    int fswz = (gr ^ (frow & 3) ^ ((frow >> 2) & 3)) * 8;

    int reg0 = wave * 2;
    int arow0 = m0 + reg0 * 16 + srow;
    arow0 = arow0 < TTOK ? arow0 : TTOK - 1;
    int arow1 = m0 + (reg0 + 1) * 16 + srow;
    arow1 = arow1 < TTOK ? arow1 : TTOK - 1;
    const unsigned short* aptr0 = A + (size_t)arow0 * K + scol;
    const unsigned short* aptr1 = A + (size_t)arow1 * K + scol;
    // B: 64 rows staged by 4 waves, 1 call per half: wave w -> rows w*16 + srow
    const unsigned short* bptrw = Bte + (size_t)(n0 + wave * 16 + srow) * K + scol;

    #pragma unroll
    for (int kc = 0; kc < K; kc += 64) {
        #pragma unroll
        for (int p = 0; p < 2; p++) {
            gl_lds16(aptr0 + kc + p * 32, &As[p * 4096 + reg0 * 512]);
            gl_lds16(aptr1 + kc + p * 32, &As[p * 4096 + (reg0 + 1) * 512]);
            gl_lds16(bptrw + kc + p * 32, &Bs[p * 2048 + wave * 512]);
        }
        __syncthreads();
        #pragma unroll
        for (int p = 0; p < 2; p++) {
            short8_t af[4], bfr[2];
            #pragma unroll
            for (int i = 0; i < 4; i++)
                af[i] = *(const short8_t*)&As[p * 4096 + (wm + i * 16 + frow) * 32 + fswz];
            #pragma unroll
            for (int j = 0; j < 2; j++)
                bfr[j] = *(const short8_t*)&Bs[p * 2048 + (wn + j * 16 + frow) * 32 + fswz];
            #pragma unroll
            for (int i = 0; i < 4; i++)
                #pragma unroll
                for (int j = 0; j < 2; j++)
                    acc[i][j] = __builtin_amdgcn_mfma_f32_16x16x32_bf16(af[i], bfr[j], acc[i][j], 0, 0, 0);
        }
        __syncthreads();
    }

    int quad = lane >> 4;
    int colb = lane & 15;
    float bv[2];
    #pragma unroll
    for (int j = 0; j < 2; j++) bv[j] = bias[(size_t)e * N + n0 + wn + j * 16 + colb];

    #pragma unroll
    for (int i = 0; i < 4; i++) {
        #pragma unroll
        for (int j = 0; j < 2; j++) {
            int col = n0 + wn + j * 16 + colb;
            #pragma unroll
            for (int r = 0; r < 4; r++) {
                int row = m0 + wm + i * 16 + quad * 4 + r;
                if (row < seg1) {
                    float v = acc[i][j][r] + bv[j];
                    C[(size_t)row * N + col] = v;
                }
            }
        }
    }
}

extern "C" void kernel_launch(void* const* d_in, const int* in_sizes, int n_in,
                              void* d_out, int out_size, void* d_ws, size_t ws_size,
                              hipStream_t stream) {
    const float* x  = (const float*)d_in[0];
    const float* Wg = (const float*)d_in[1];
    const float* bg = (const float*)d_in[2];
    const float* W1 = (const float*)d_in[3];
    const float* b1 = (const float*)d_in[4];
    const float* W2 = (const float*)d_in[5];
    const float* b2 = (const float*)d_in[6];
    float* out = (float*)d_out;

    char* ws = (char*)d_ws;
    size_t off = 0;
    auto alloc = [&](size_t bytes) -> char* {
        char* p = ws + off;
        off += (bytes + 255) & ~(size_t)255;
        return p;
    };
    unsigned short* W1T = (unsigned short*)alloc((size_t)NEXP * DDIM * FFDIM * 2);  // [E][FF][D]
    unsigned short* W2T = (unsigned short*)alloc((size_t)NEXP * DDIM * FFDIM * 2);  // [E][D][FF]
    unsigned short* Xs  = (unsigned short*)alloc((size_t)TTOK * DDIM * 2);          // sorted tokens
    unsigned short* H   = (unsigned short*)alloc((size_t)TTOK * FFDIM * 2);         // hidden
    int*   route        = (int*)alloc((size_t)TTOK * 4);
    float* pmaxArr      = (float*)alloc((size_t)TTOK * 4);
    int*   blockCounts  = (int*)alloc((size_t)NGB * NEXP * 4);
    int*   segPrefix    = (int*)alloc((size_t)(NEXP + 1) * 4);
    int*   tilePrefix   = (int*)alloc((size_t)(NEXP + 1) * 4);

    // 1: fused gate + fast W1-transpose (5120 blocks)
    prep_kernel<<<NGB + TRW1_BLOCKS, 256, 0, stream>>>(
        x, Wg, bg, route, pmaxArr, blockCounts, W1, W1T);
    // 2: scatter with inlined offset reduction (also publishes seg/tile prefixes)
    scatter_kernel<<<NGB, 256, 0, stream>>>(
        x, route, pmaxArr, blockCounts, Xs, segPrefix, tilePrefix);
    // 3: H = relu(Xs @ W1[e] + b1[e]) (bf16) WITH W2-transpose hidden in extra blocks
    gemm1_fused<<<dim3(MAXTILES + TRW2_XBLK, FFDIM / 128, 1), 256, 0, stream>>>(
        Xs, W1T, b1, H, segPrefix, tilePrefix, W2, W2T);
    // 4: out = H @ W2[e] + b2[e] (fp32), 128x64 tiles, grid (136, 8)
    gemm2_seg<<<dim3(MAXTILES, DDIM / 64, 1), 256, 0, stream>>>(
        H, W2T, b2, out, segPrefix, tilePrefix);
}

// Round 7
// 286.222 us; speedup vs baseline: 1.0614x; 1.0614x over previous
//
#include <hip/hip_runtime.h>
#include <hip/hip_bf16.h>

constexpr int TTOK  = 16384;   // B*S = 8*2048
constexpr int DDIM  = 512;
constexpr int FFDIM = 2048;
constexpr int NEXP  = 8;
constexpr int GB_TOK = 16;             // tokens per gate/scatter block
constexpr int NGB    = TTOK / GB_TOK;  // 1024
constexpr int MAXTILES = TTOK / 128 + NEXP;  // 136: worst-case M-tiles over all experts
constexpr int TRW1_BLOCKS = 4096;      // 512 tiles/expert * 8 (64x32 tiles), piggyback on scatter
constexpr int TRW2_XBLK   = 256;       // x-extent of W2-transpose range in gemm1 grid (x16 y = 4096)

typedef __attribute__((ext_vector_type(8))) short short8_t;
typedef __attribute__((ext_vector_type(4))) float f32x4_t;

__device__ __forceinline__ unsigned short f2bf(float f) {
    union { float f; unsigned u; } v; v.f = f;
    return (unsigned short)((v.u + 0x7fffu + ((v.u >> 16) & 1u)) >> 16);  // RNE
}

__device__ __forceinline__ void gl_lds16(const void* g, void* l) {
    __builtin_amdgcn_global_load_lds(
        (const __attribute__((address_space(1))) void*)g,
        (__attribute__((address_space(3))) void*)l,
        16, 0, 0);
}

// ---------------- fast 64(r)x32(c) transpose+cast tile (proven R4)
__device__ __forceinline__ void tr_tile(const float* __restrict__ src,
                                        unsigned short* __restrict__ dst,
                                        int R, int C, int tileId, float* lds) {
    int tilesC = C / 32;
    int c0 = (tileId % tilesC) * 32;
    int r0 = (tileId / tilesC) * 64;
    int t = threadIdx.x;
    int lr = t >> 3;            // 0..31
    int ls = t & 7;             // float4 slot
    #pragma unroll
    for (int rb = 0; rb < 2; rb++) {
        int row = rb * 32 + lr;
        float4 v = *(const float4*)(src + (size_t)(r0 + row) * C + c0 + 4 * ls);
        int p4 = (4 * ls) ^ (8 * ((row >> 3) & 3));
        *(float4*)(lds + row * 36 + p4) = v;
    }
    __syncthreads();
    int c = t >> 3;             // dst row (= src col) 0..31
    int b = t & 7;              // r-block
    union { short8_t v; unsigned short s[8]; } o;
    #pragma unroll
    for (int j = 0; j < 8; j++) {
        int r = 8 * b + j;
        int p = c ^ (8 * ((r >> 3) & 3));
        o.s[j] = f2bf(lds[r * 36 + p]);
    }
    *(short8_t*)(dst + (size_t)(c0 + c) * R + r0 + 8 * b) = o.v;
}

// ---------------- gate-only prep: Wg in registers, f64 logit accum, f32 softmax tail
__global__ __launch_bounds__(256) void gate_kernel(const float* __restrict__ x,
                                                   const float* __restrict__ Wg,
                                                   const float* __restrict__ bg,
                                                   int* __restrict__ route,
                                                   float* __restrict__ pmax,
                                                   int* __restrict__ blockCounts) {
    int tid = threadIdx.x;
    __shared__ int cnt[NEXP];
    __shared__ float bgs[NEXP];
    int gb = blockIdx.x;
    if (tid < NEXP) { cnt[tid] = 0; bgs[tid] = bg[tid]; }
    __syncthreads();
    int wave = tid >> 6, lane = tid & 63;
    float w[8][8];
    #pragma unroll
    for (int jj = 0; jj < 8; jj++) {
        float4 a = *(const float4*)(Wg + (size_t)(lane * 8 + jj) * NEXP);
        float4 b = *(const float4*)(Wg + (size_t)(lane * 8 + jj) * NEXP + 4);
        w[jj][0] = a.x; w[jj][1] = a.y; w[jj][2] = a.z; w[jj][3] = a.w;
        w[jj][4] = b.x; w[jj][5] = b.y; w[jj][6] = b.z; w[jj][7] = b.w;
    }
    int tbase = gb * GB_TOK + wave * 4;
    for (int it = 0; it < 4; it++) {
        int t = tbase + it;
        float4 xa = *(const float4*)(x + (size_t)t * DDIM + lane * 8);
        float4 xb = *(const float4*)(x + (size_t)t * DDIM + lane * 8 + 4);
        float xs[8] = {xa.x, xa.y, xa.z, xa.w, xb.x, xb.y, xb.z, xb.w};
        double acc[NEXP];
        #pragma unroll
        for (int e = 0; e < NEXP; e++) acc[e] = 0.0;
        #pragma unroll
        for (int jj = 0; jj < 8; jj++) {
            double xv = (double)xs[jj];
            #pragma unroll
            for (int e = 0; e < NEXP; e++) acc[e] += xv * (double)w[jj][e];
        }
        #pragma unroll
        for (int off = 32; off > 0; off >>= 1) {
            #pragma unroll
            for (int e = 0; e < NEXP; e++) acc[e] += __shfl_down(acc[e], off);
        }
        if (lane == 0) {
            double l[NEXP];
            #pragma unroll
            for (int e = 0; e < NEXP; e++) l[e] = acc[e] + (double)bgs[e];
            int r = 0; double lm = l[0];
            #pragma unroll
            for (int e = 1; e < NEXP; e++) if (l[e] > lm) { lm = l[e]; r = e; }
            float s = 0.0f;                          // f32 softmax (matches f32 reference)
            #pragma unroll
            for (int e = 0; e < NEXP; e++) s += __expf((float)(l[e] - lm));
            route[t] = r;
            pmax[t] = 1.0f / s;
            atomicAdd(&cnt[r], 1);
        }
    }
    __syncthreads();
    if (tid < NEXP) blockCounts[gb * NEXP + tid] = cnt[tid];
}

// ---------------- scatter (inline scan) + piggybacked W1 transpose.
// Blocks [0,NGB): token permute+scale+cast (inlines offset reduction, publishes
// seg/tile prefixes). Blocks [NGB, NGB+4096): W1 64x32 transpose tiles — the
// ~23 us of W1-transpose traffic hides under/beside the scatter's streaming.
__global__ __launch_bounds__(256) void scatter_kernel(const float* __restrict__ x,
                                                      const int* __restrict__ route,
                                                      const float* __restrict__ pmax,
                                                      const int* __restrict__ blockCounts,
                                                      unsigned short* __restrict__ Xs,
                                                      int* __restrict__ segPrefix,
                                                      int* __restrict__ tilePrefix,
                                                      const float* __restrict__ W1,
                                                      unsigned short* __restrict__ W1T) {
    int tid = threadIdx.x;
    if (blockIdx.x >= NGB) {
        __shared__ __align__(16) float tlds[64 * 36];
        int id = blockIdx.x - NGB;             // 0..4095
        int e = id >> 9;                       // 512 tiles per expert
        int tile = id & 511;
        tr_tile(W1 + (size_t)e * DDIM * FFDIM, W1T + (size_t)e * DDIM * FFDIM,
                DDIM, FFDIM, tile, tlds);
        return;
    }
    int bb = blockIdx.x;
    int wave = tid >> 6, lane = tid & 63;

    int tot[NEXP], pre[NEXP];
    #pragma unroll
    for (int e = 0; e < NEXP; e++) { tot[e] = 0; pre[e] = 0; }
    for (int b = tid; b < NGB; b += 256) {
        #pragma unroll
        for (int e = 0; e < NEXP; e++) {
            int c = blockCounts[b * NEXP + e];
            tot[e] += c;
            if (b < bb) pre[e] += c;
        }
    }
    #pragma unroll
    for (int off = 32; off > 0; off >>= 1) {
        #pragma unroll
        for (int e = 0; e < NEXP; e++) {
            tot[e] += __shfl_down(tot[e], off);
            pre[e] += __shfl_down(pre[e], off);
        }
    }
    __shared__ int stot[4][NEXP], spre[4][NEXP];
    __shared__ int boff[NEXP];
    if (lane == 0) {
        #pragma unroll
        for (int e = 0; e < NEXP; e++) { stot[wave][e] = tot[e]; spre[wave][e] = pre[e]; }
    }
    __syncthreads();
    if (tid == 0) {
        int T[NEXP], P[NEXP];
        #pragma unroll
        for (int e = 0; e < NEXP; e++) {
            T[e] = stot[0][e] + stot[1][e] + stot[2][e] + stot[3][e];
            P[e] = spre[0][e] + spre[1][e] + spre[2][e] + spre[3][e];
        }
        int s = 0;
        #pragma unroll
        for (int e = 0; e < NEXP; e++) { boff[e] = s + P[e]; s += T[e]; }
        if (bb == 0) {
            int ss = 0, tp = 0;
            segPrefix[0] = 0; tilePrefix[0] = 0;
            #pragma unroll
            for (int e = 0; e < NEXP; e++) {
                ss += T[e]; tp += (T[e] + 127) >> 7;
                segPrefix[e + 1] = ss; tilePrefix[e + 1] = tp;
            }
        }
    }
    __syncthreads();

    __shared__ int dstL[GB_TOK];
    __shared__ float pmL[GB_TOK];
    if (tid < GB_TOK) {
        int t = bb * GB_TOK + tid;
        int r = route[t];
        unsigned long long ltmask = (tid == 0) ? 0ull : ((~0ull) >> (64 - tid));
        int rank = 0;
        #pragma unroll
        for (int e = 0; e < NEXP; e++) {
            unsigned long long m = __ballot(r == e);
            if (r == e) rank = __popcll(m & ltmask);
        }
        dstL[tid] = boff[r] + rank;
        pmL[tid] = pmax[t];
    }
    __syncthreads();
    for (int rr = 0; rr < 4; rr++) {
        int rowl = wave * 4 + rr;
        int t = bb * GB_TOK + rowl;
        float pm = pmL[rowl];
        const float4* xr = (const float4*)(x + (size_t)t * DDIM) + lane * 2;
        float4 a = xr[0], b = xr[1];
        union { short8_t v; unsigned short s[8]; } o;
        o.s[0] = f2bf(a.x * pm); o.s[1] = f2bf(a.y * pm);
        o.s[2] = f2bf(a.z * pm); o.s[3] = f2bf(a.w * pm);
        o.s[4] = f2bf(b.x * pm); o.s[5] = f2bf(b.y * pm);
        o.s[6] = f2bf(b.z * pm); o.s[7] = f2bf(b.w * pm);
        *(short8_t*)(Xs + (size_t)dstL[rowl] * DDIM + lane * 8) = o.v;
    }
}

// ============================================================================
// GEMM1 fused (proven R4): 128x128/BK=64 2-barrier structure + W2-transpose
// piggyback blocks sharing one 32 KB SMEM region. bf16 out + ReLU + bias.
// ============================================================================
__global__ __launch_bounds__(256) void gemm1_fused(const unsigned short* __restrict__ A,
                                                   const unsigned short* __restrict__ Bt,
                                                   const float* __restrict__ bias,
                                                   unsigned short* __restrict__ C,
                                                   const int* __restrict__ segPrefix,
                                                   const int* __restrict__ tilePrefix,
                                                   const float* __restrict__ W2,
                                                   unsigned short* __restrict__ W2T) {
    constexpr int K = DDIM, N = FFDIM;
    __shared__ __align__(16) unsigned short SMEM[16384];   // 32 KB shared by both roles

    if (blockIdx.x >= MAXTILES) {
        int id = (blockIdx.x - MAXTILES) * 16 + blockIdx.y;  // 0..4095
        int e = id >> 9;
        int tile = id & 511;
        tr_tile(W2 + (size_t)e * DDIM * FFDIM, W2T + (size_t)e * DDIM * FFDIM,
                FFDIM, DDIM, tile, (float*)SMEM);
        return;
    }

    int bx = blockIdx.x;
    bx = (bx & 7) * (MAXTILES / 8) + (bx >> 3);   // bijective XCD chunking (136 % 8 == 0)
    int t = bx;
    if (t >= tilePrefix[NEXP]) return;
    int e = 0;
    #pragma unroll
    for (int i = 1; i <= NEXP; i++) e += (t >= tilePrefix[i]) ? 1 : 0;
    int seg1 = segPrefix[e + 1];
    int m0 = segPrefix[e] + (t - tilePrefix[e]) * 128;
    int n0 = blockIdx.y * 128;

    unsigned short* As = SMEM;
    unsigned short* Bs = SMEM + 8192;

    int tid = threadIdx.x, wave = tid >> 6, lane = tid & 63;
    const unsigned short* Bte = Bt + (size_t)e * N * K;

    int srow = lane >> 2;
    int sg   = (lane & 3) ^ ((lane >> 2) & 3) ^ ((lane >> 4) & 3);
    int scol = sg * 8;

    f32x4_t acc[4][4];
    #pragma unroll
    for (int i = 0; i < 4; i++)
        #pragma unroll
        for (int j = 0; j < 4; j++) acc[i][j] = (f32x4_t){0.f, 0.f, 0.f, 0.f};

    int wm = (wave & 1) * 64;
    int wn = (wave >> 1) * 64;
    int frow = lane & 15;
    int gr = lane >> 4;
    int fswz = (gr ^ (frow & 3) ^ ((frow >> 2) & 3)) * 8;

    int reg0 = wave * 2;
    int arow0 = m0 + reg0 * 16 + srow;
    arow0 = arow0 < TTOK ? arow0 : TTOK - 1;
    int arow1 = m0 + (reg0 + 1) * 16 + srow;
    arow1 = arow1 < TTOK ? arow1 : TTOK - 1;
    const unsigned short* aptr0 = A + (size_t)arow0 * K + scol;
    const unsigned short* aptr1 = A + (size_t)arow1 * K + scol;
    const unsigned short* bptr0 = Bte + (size_t)(n0 + reg0 * 16 + srow) * K + scol;
    const unsigned short* bptr1 = Bte + (size_t)(n0 + (reg0 + 1) * 16 + srow) * K + scol;

    #pragma unroll
    for (int kc = 0; kc < K; kc += 64) {
        #pragma unroll
        for (int p = 0; p < 2; p++) {
            gl_lds16(aptr0 + kc + p * 32, &As[p * 4096 + reg0 * 512]);
            gl_lds16(aptr1 + kc + p * 32, &As[p * 4096 + (reg0 + 1) * 512]);
            gl_lds16(bptr0 + kc + p * 32, &Bs[p * 4096 + reg0 * 512]);
            gl_lds16(bptr1 + kc + p * 32, &Bs[p * 4096 + (reg0 + 1) * 512]);
        }
        __syncthreads();
        #pragma unroll
        for (int p = 0; p < 2; p++) {
            short8_t af[4], bfr[4];
            #pragma unroll
            for (int i = 0; i < 4; i++)
                af[i] = *(const short8_t*)&As[p * 4096 + (wm + i * 16 + frow) * 32 + fswz];
            #pragma unroll
            for (int j = 0; j < 4; j++)
                bfr[j] = *(const short8_t*)&Bs[p * 4096 + (wn + j * 16 + frow) * 32 + fswz];
            #pragma unroll
            for (int i = 0; i < 4; i++)
                #pragma unroll
                for (int j = 0; j < 4; j++)
                    acc[i][j] = __builtin_amdgcn_mfma_f32_16x16x32_bf16(af[i], bfr[j], acc[i][j], 0, 0, 0);
        }
        __syncthreads();
    }

    int quad = lane >> 4;
    int colb = lane & 15;
    float bv[4];
    #pragma unroll
    for (int j = 0; j < 4; j++) bv[j] = bias[(size_t)e * N + n0 + wn + j * 16 + colb];

    unsigned short* cbuf = As;
    #pragma unroll
    for (int p = 0; p < 2; p++) {
        __syncthreads();
        if ((wave >> 1) == p) {
            #pragma unroll
            for (int i = 0; i < 4; i++)
                #pragma unroll
                for (int j = 0; j < 4; j++)
                    #pragma unroll
                    for (int r = 0; r < 4; r++) {
                        float v = acc[i][j][r] + bv[j];
                        v = fmaxf(v, 0.0f);
                        int wrow = wm + i * 16 + quad * 4 + r;
                        int cc = (j * 16 + colb) ^ (((wrow >> 3) & 1) * 16);
                        cbuf[wrow * 72 + cc] = f2bf(v);
                    }
        }
        __syncthreads();
        int row = tid >> 1, ch = (tid & 1) * 32;
        int grow = m0 + row;
        if (grow < seg1) {
            #pragma unroll
            for (int k = 0; k < 4; k++) {
                int vv = (ch + k * 8) ^ (((row >> 3) & 1) * 16);
                short8_t v = *(const short8_t*)&cbuf[row * 72 + vv];
                *(short8_t*)&C[(size_t)grow * N + n0 + p * 64 + ch + k * 8] = v;
            }
        }
    }
}

// ---------------- GEMM2 (proven R0/R3/R4): 128x128, fp32 out + XCD swizzle
template <bool RELU, typename OutT, int K, int N>
__global__ __launch_bounds__(256) void gemm_seg(const unsigned short* __restrict__ A,
                                                const unsigned short* __restrict__ Bt,
                                                const float* __restrict__ bias,
                                                OutT* __restrict__ C,
                                                const int* __restrict__ segPrefix,
                                                const int* __restrict__ tilePrefix) {
    int bx = blockIdx.x;
    bx = (bx & 7) * (MAXTILES / 8) + (bx >> 3);
    int t = bx;
    if (t >= tilePrefix[NEXP]) return;
    int e = 0;
    #pragma unroll
    for (int i = 1; i <= NEXP; i++) e += (t >= tilePrefix[i]) ? 1 : 0;
    int seg1 = segPrefix[e + 1];
    int m0 = segPrefix[e] + (t - tilePrefix[e]) * 128;
    int n0 = blockIdx.y * 128;

    __shared__ unsigned short As[2 * 4096];
    __shared__ unsigned short Bs[2 * 4096];

    int tid = threadIdx.x, wave = tid >> 6, lane = tid & 63;
    const unsigned short* Bte = Bt + (size_t)e * N * K;

    int srow = lane >> 2;
    int sg   = (lane & 3) ^ ((lane >> 2) & 3) ^ ((lane >> 4) & 3);
    int scol = sg * 8;

    f32x4_t acc[4][4];
    #pragma unroll
    for (int i = 0; i < 4; i++)
        #pragma unroll
        for (int j = 0; j < 4; j++) acc[i][j] = (f32x4_t){0.f, 0.f, 0.f, 0.f};

    int wm = (wave & 1) * 64;
    int wn = (wave >> 1) * 64;
    int frow = lane & 15;
    int gr = lane >> 4;
    int fswz = (gr ^ (frow & 3) ^ ((frow >> 2) & 3)) * 8;

    int reg0 = wave * 2;
    int arow0 = m0 + reg0 * 16 + srow;
    arow0 = arow0 < TTOK ? arow0 : TTOK - 1;
    int arow1 = m0 + (reg0 + 1) * 16 + srow;
    arow1 = arow1 < TTOK ? arow1 : TTOK - 1;
    const unsigned short* aptr0 = A + (size_t)arow0 * K + scol;
    const unsigned short* aptr1 = A + (size_t)arow1 * K + scol;
    const unsigned short* bptr0 = Bte + (size_t)(n0 + reg0 * 16 + srow) * K + scol;
    const unsigned short* bptr1 = Bte + (size_t)(n0 + (reg0 + 1) * 16 + srow) * K + scol;

    #pragma unroll
    for (int kc = 0; kc < K; kc += 64) {
        #pragma unroll
        for (int p = 0; p < 2; p++) {
            gl_lds16(aptr0 + kc + p * 32, &As[p * 4096 + reg0 * 512]);
            gl_lds16(aptr1 + kc + p * 32, &As[p * 4096 + (reg0 + 1) * 512]);
            gl_lds16(bptr0 + kc + p * 32, &Bs[p * 4096 + reg0 * 512]);
            gl_lds16(bptr1 + kc + p * 32, &Bs[p * 4096 + (reg0 + 1) * 512]);
        }
        __syncthreads();
        #pragma unroll
        for (int p = 0; p < 2; p++) {
            short8_t af[4], bfr[4];
            #pragma unroll
            for (int i = 0; i < 4; i++)
                af[i] = *(const short8_t*)&As[p * 4096 + (wm + i * 16 + frow) * 32 + fswz];
            #pragma unroll
            for (int j = 0; j < 4; j++)
                bfr[j] = *(const short8_t*)&Bs[p * 4096 + (wn + j * 16 + frow) * 32 + fswz];
            #pragma unroll
            for (int i = 0; i < 4; i++)
                #pragma unroll
                for (int j = 0; j < 4; j++)
                    acc[i][j] = __builtin_amdgcn_mfma_f32_16x16x32_bf16(af[i], bfr[j], acc[i][j], 0, 0, 0);
        }
        __syncthreads();
    }

    int quad = lane >> 4;
    int colb = lane & 15;
    float bv[4];
    #pragma unroll
    for (int j = 0; j < 4; j++) bv[j] = bias[(size_t)e * N + n0 + wn + j * 16 + colb];

    #pragma unroll
    for (int i = 0; i < 4; i++) {
        #pragma unroll
        for (int j = 0; j < 4; j++) {
            int col = n0 + wn + j * 16 + colb;
            #pragma unroll
            for (int r = 0; r < 4; r++) {
                int row = m0 + wm + i * 16 + quad * 4 + r;
                if (row < seg1) {
                    float v = acc[i][j][r] + bv[j];
                    if (RELU) v = fmaxf(v, 0.0f);
                    C[(size_t)row * N + col] = v;
                }
            }
        }
    }
}

extern "C" void kernel_launch(void* const* d_in, const int* in_sizes, int n_in,
                              void* d_out, int out_size, void* d_ws, size_t ws_size,
                              hipStream_t stream) {
    const float* x  = (const float*)d_in[0];
    const float* Wg = (const float*)d_in[1];
    const float* bg = (const float*)d_in[2];
    const float* W1 = (const float*)d_in[3];
    const float* b1 = (const float*)d_in[4];
    const float* W2 = (const float*)d_in[5];
    const float* b2 = (const float*)d_in[6];
    float* out = (float*)d_out;

    char* ws = (char*)d_ws;
    size_t off = 0;
    auto alloc = [&](size_t bytes) -> char* {
        char* p = ws + off;
        off += (bytes + 255) & ~(size_t)255;
        return p;
    };
    unsigned short* W1T = (unsigned short*)alloc((size_t)NEXP * DDIM * FFDIM * 2);  // [E][FF][D]
    unsigned short* W2T = (unsigned short*)alloc((size_t)NEXP * DDIM * FFDIM * 2);  // [E][D][FF]
    unsigned short* Xs  = (unsigned short*)alloc((size_t)TTOK * DDIM * 2);          // sorted tokens
    unsigned short* H   = (unsigned short*)alloc((size_t)TTOK * FFDIM * 2);         // hidden
    int*   route        = (int*)alloc((size_t)TTOK * 4);
    float* pmaxArr      = (float*)alloc((size_t)TTOK * 4);
    int*   blockCounts  = (int*)alloc((size_t)NGB * NEXP * 4);
    int*   segPrefix    = (int*)alloc((size_t)(NEXP + 1) * 4);
    int*   tilePrefix   = (int*)alloc((size_t)(NEXP + 1) * 4);

    // 1: gate only (1024 blocks) — shortest possible critical-path head
    gate_kernel<<<NGB, 256, 0, stream>>>(x, Wg, bg, route, pmaxArr, blockCounts);
    // 2: scatter (inline scan) + piggybacked W1-transpose (5120 blocks)
    scatter_kernel<<<NGB + TRW1_BLOCKS, 256, 0, stream>>>(
        x, route, pmaxArr, blockCounts, Xs, segPrefix, tilePrefix, W1, W1T);
    // 3: H = relu(Xs @ W1[e] + b1[e]) (bf16) WITH W2-transpose hidden in extra blocks
    gemm1_fused<<<dim3(MAXTILES + TRW2_XBLK, FFDIM / 128, 1), 256, 0, stream>>>(
        Xs, W1T, b1, H, segPrefix, tilePrefix, W2, W2T);
    // 4: out = H @ W2[e] + b2[e] (fp32), 128x128 tiles (proven), grid (136, 4)
    gemm_seg<false, float, FFDIM, DDIM><<<dim3(MAXTILES, DDIM / 128, 1), 256, 0, stream>>>(
        H, W2T, b2, out, segPrefix, tilePrefix);
}